// Round 6
// baseline (539.378 us; speedup 1.0000x reference)
//
#include <hip/hip_runtime.h>
#include <hip/hip_bf16.h>
#include <cstddef>
#include <cfloat>

#define NW 80000
#define ND 16000
#define EWW 200000
#define EWD 200000

typedef short v8s __attribute__((ext_vector_type(8)));
typedef float v4f __attribute__((ext_vector_type(4)));

static __device__ __forceinline__ float blo(unsigned u) { return __uint_as_float(u << 16); }
static __device__ __forceinline__ float bhi(unsigned u) { return __uint_as_float(u & 0xffff0000u); }

// async global->LDS 16B copy: lane i of the wave writes lds_base + i*16
static __device__ __forceinline__ void gl2lds16(const void* g, void* l) {
    __builtin_amdgcn_global_load_lds((__attribute__((address_space(1))) void*)g,
                                     (__attribute__((address_space(3))) void*)l, 16, 0, 0);
}

// ---------- fused utility dispatch: cast + weight prep (both layers) + deg zeroing ----
// blocks [0,20000): cast xw fp32->bf16 (x4)
// [20000,21024): transpose L0 -> Wt0 ; [21024,21536): transpose L1 -> Wt1
// [21536,21540): make_wr L0 ; [21540,21542): make_wr L1
// [21542,21730): zero deg arrays (contiguous int4 region)
__global__ __launch_bounds__(256) void util_all(
        const float4* __restrict__ xw4, uint2* __restrict__ xwb,
        const float* __restrict__ W_ww0, const float* __restrict__ W_wd0,
        const float* __restrict__ W_ww1, const float* __restrict__ W_wd1,
        const float* __restrict__ ar_wd0, const float* __restrict__ ar_wd1,
        __hip_bfloat16* __restrict__ Wt0, __hip_bfloat16* __restrict__ Wt1,
        float* __restrict__ Wr0, float* __restrict__ Wr1,
        int4* __restrict__ degz) {
    int bid = blockIdx.x, tid = threadIdx.x;
    if (bid < 20000) {
        int i = bid * 256 + tid;                 // 5,120,000 exactly
        float4 v = xw4[i];
        __hip_bfloat162 a, b;
        a.x = __float2bfloat16(v.x); a.y = __float2bfloat16(v.y);
        b.x = __float2bfloat16(v.z); b.y = __float2bfloat16(v.w);
        uint2 o;
        o.x = *(unsigned*)&a; o.y = *(unsigned*)&b;
        xwb[i] = o;
    } else if (bid < 21024) {
        int i = (bid - 20000) * 256 + tid;       // 1024*256, K=256
        int n = i >> 8, k = i & 255;
        float v = (n < 512) ? W_ww0[k * 512 + n] : W_wd0[k * 512 + (n - 512)];
        Wt0[n * 256 + k] = __float2bfloat16(v);
    } else if (bid < 21536) {
        int i = (bid - 21024) * 256 + tid;       // 1024*128, K=128
        int n = i >> 7, k = i & 127;
        float v = (n < 512) ? W_ww1[k * 512 + n] : W_wd1[k * 512 + (n - 512)];
        Wt1[n * 128 + k] = __float2bfloat16(v);
    } else if (bid < 21540) {
        int i = (bid - 21536) * 256 + tid;       // 256*4
        int k = i >> 2, h = i & 3;
        float sr = 0.f;
        const float* wr = W_wd0 + (size_t)k * 512 + h * 128;
        const float* arr = ar_wd0 + h * 128;
        for (int f = 0; f < 128; f++) sr += wr[f] * arr[f];
        Wr0[k * 4 + h] = sr;
    } else if (bid < 21542) {
        int i = (bid - 21540) * 256 + tid;       // 128*4
        int k = i >> 2, h = i & 3;
        float sr = 0.f;
        const float* wr = W_wd1 + (size_t)k * 512 + h * 128;
        const float* arr = ar_wd1 + h * 128;
        for (int f = 0; f < 128; f++) sr += wr[f] * arr[f];
        Wr1[k * 4 + h] = sr;
    } else {
        int idx = (bid - 21542) * 256 + tid;     // 48000 int4 = 192000 ints
        if (idx < 48000) degz[idx] = make_int4(0, 0, 0, 0);
    }
}

// ---------- merged bf16 MFMA GEMM (both relations) + attention-logit epilogue
//            + fused doc-side attn GEMV as extra grid blocks ----------
// z[M,1024] = A[M,K] @ [W_ww | W_wd]  (Bt = concat^T [1024,K]).  BM=128, BK=64.
// Wave grid 4x2: wave (wr,wc) owns 32 rows x 64 cols -> per kh 2 A-frags + 4
// B-frags feed 8 MFMAs (0.75 ds_read/MFMA vs 1.125 in the 8x16-row layout;
// LDS read traffic 144->96 KB per block-K-step). T3+T4 counted-vmcnt pipeline,
// T5 setprio. el/er epilogue spans the two wc-halves of each row: partials
// combined through LDS under the (single) writeback barrier.
// Blocks [GB, GB+(Natt+7)/8): doc-side er GEMV (one wave per row), riding in
// this dispatch to avoid a separate launch + gap.
__global__ __launch_bounds__(512) void gemm_epi(const __hip_bfloat16* __restrict__ A,
                                                const __hip_bfloat16* __restrict__ Bt,
                                                __hip_bfloat16* __restrict__ C,
                                                const float* __restrict__ al0,
                                                const float* __restrict__ ar0,
                                                const float* __restrict__ al1,
                                                float* __restrict__ el0,
                                                float* __restrict__ er0,
                                                float* __restrict__ el1,
                                                int M, int K,
                                                const float* __restrict__ xatt_f,
                                                const __hip_bfloat16* __restrict__ xatt_b,
                                                const float* __restrict__ Wv,
                                                float* __restrict__ er_att, int Natt) {
    const int N = 1024;
    __shared__ short AsF[2][128 * 64];   // 2 x 16 KB, row stride 64 shorts
    __shared__ short BsF[2][128 * 64];
    int tid = threadIdx.x;
    int wave = tid >> 6, lane = tid & 63;
    int l16 = lane & 15, quad = lane >> 4;

    int MT = M >> 7;
    int GB = MT * 8;                     // gemm blocks
    if ((int)blockIdx.x >= GB) {
        // ---------- fused doc-side attention GEMV: one wave per row ----------
        int row = ((int)blockIdx.x - GB) * 8 + wave;
        if (row >= Natt) return;
        float a0 = 0.f, a1 = 0.f, a2 = 0.f, a3 = 0.f;
        if (xatt_f) {
            const float* xr = xatt_f + (size_t)row * K;
            for (int k = lane; k < K; k += 64) {
                float v = xr[k];
                const float* w = Wv + k * 4;
                a0 += v * w[0]; a1 += v * w[1]; a2 += v * w[2]; a3 += v * w[3];
            }
        } else {
            const __hip_bfloat16* xr = xatt_b + (size_t)row * K;
            for (int k = lane; k < K; k += 64) {
                float v = __bfloat162float(xr[k]);
                const float* w = Wv + k * 4;
                a0 += v * w[0]; a1 += v * w[1]; a2 += v * w[2]; a3 += v * w[3];
            }
        }
#pragma unroll
        for (int off = 32; off; off >>= 1) {
            a0 += __shfl_down(a0, off); a1 += __shfl_down(a1, off);
            a2 += __shfl_down(a2, off); a3 += __shfl_down(a3, off);
        }
        if (lane == 0) {
            er_att[row * 4 + 0] = a0; er_att[row * 4 + 1] = a1;
            er_att[row * 4 + 2] = a2; er_att[row * 4 + 3] = a3;
        }
        return;
    }

    // ---- XCD swizzle ----
    int full = MT >> 3;
    int bid = blockIdx.x;
    int h, mt;
    if (bid < (full << 6)) {
        int s = bid >> 6, r = bid & 63;
        h = r >> 3;
        mt = (s << 3) | (r & 7);
    } else {
        int r2 = bid - (full << 6);
        int rem = MT - (full << 3);
        h = r2 / rem;
        mt = (full << 3) + (r2 - h * rem);
    }
    bool isww = h < 4;
    int hh = isww ? h : h - 4;
    int bm = mt * 128, bn = h * 128;

    int wr = wave >> 1, wc = wave & 1;   // 4 row-groups x 2 col-halves
    v4f acc[2][4] = {};

    int laneR = lane >> 3;                 // 0..7
    int laneC = (lane & 7) ^ laneR;        // swizzled 16B-chunk index
    const __hip_bfloat16* ga = A  + (size_t)(bm + wave * 16 + laneR) * K + laneC * 8;
    const __hip_bfloat16* gb = Bt + (size_t)(bn + wave * 16 + laneR) * K + laneC * 8;
    int lofs = (wave * 16) * 64;           // staging: wave-private 16-row slab

    auto STAGE = [&](int buf, int k0) {
#pragma unroll
        for (int j = 0; j < 2; j++) {
            gl2lds16(ga + (size_t)(j * 8) * K + k0, &AsF[buf][lofs + j * 512]);
            gl2lds16(gb + (size_t)(j * 8) * K + k0, &BsF[buf][lofs + j * 512]);
        }
    };
    auto COMPUTE = [&](int buf) {
#pragma unroll
        for (int kh = 0; kh < 2; kh++) {
            int s = (kh * 4 + quad) ^ (l16 & 7);
            v8s a[2], b[4];
#pragma unroll
            for (int rr = 0; rr < 2; rr++)
                a[rr] = *(const v8s*)&AsF[buf][(wr * 32 + rr * 16 + l16) * 64 + s * 8];
#pragma unroll
            for (int c = 0; c < 4; c++)
                b[c] = *(const v8s*)&BsF[buf][(wc * 64 + c * 16 + l16) * 64 + s * 8];
            __builtin_amdgcn_s_setprio(1);
#pragma unroll
            for (int rr = 0; rr < 2; rr++)
#pragma unroll
                for (int c = 0; c < 4; c++)
                    acc[rr][c] = __builtin_amdgcn_mfma_f32_16x16x32_bf16(a[rr], b[c], acc[rr][c], 0, 0, 0);
            __builtin_amdgcn_s_setprio(0);
        }
    };

    STAGE(0, 0);
    for (int k0 = 0; k0 < K; k0 += 128) {
        if (k0 + 64 < K) {
            STAGE(1, k0 + 64);
            asm volatile("s_waitcnt vmcnt(4)" ::: "memory");
        } else {
            asm volatile("s_waitcnt vmcnt(0)" ::: "memory");
        }
        __builtin_amdgcn_s_barrier();
        asm volatile("" ::: "memory");
        COMPUTE(0);
        __builtin_amdgcn_s_barrier();
        asm volatile("" ::: "memory");
        if (k0 + 128 < K) {
            STAGE(0, k0 + 128);
            asm volatile("s_waitcnt vmcnt(4)" ::: "memory");
        } else {
            asm volatile("s_waitcnt vmcnt(0)" ::: "memory");
        }
        __builtin_amdgcn_s_barrier();
        asm volatile("" ::: "memory");
        COMPUTE(1);
        __builtin_amdgcn_s_barrier();      // orders all COMPUTE reads before post-loop LDS writes
        asm volatile("" ::: "memory");
    }

    // ---- C writeback stage into LDS (rotated chunks, conflict-free) ----
    short* cs = &AsF[0][0];                // flat 32KB = [128][128] bf16
#pragma unroll
    for (int rr = 0; rr < 2; rr++)
#pragma unroll
        for (int c = 0; c < 4; c++)
#pragma unroll
            for (int i = 0; i < 4; i++) {
                int lr = wr * 32 + rr * 16 + quad * 4 + i;
                int sIdx = wc * 64 + c * 16 + l16;
                int chunk = ((sIdx >> 3) + 2 * (lr >> 2)) & 15;
                cs[lr * 128 + (chunk << 3) + (sIdx & 7)] =
                    (short)__bfloat16_as_ushort(__float2bfloat16(acc[rr][c][i]));
            }
    // ---- el/er dot over this wave's 64-col half; fp32 partials via LDS ----
    const float* alp = isww ? al0 : al1;
    float* elp = isww ? el0 : el1;
    float* erp = isww ? er0 : nullptr;
    float alv[4], arv[4];
#pragma unroll
    for (int c = 0; c < 4; c++) {
        alv[c] = alp[hh * 128 + wc * 64 + c * 16 + l16];
        arv[c] = isww ? ar0[hh * 128 + wc * 64 + c * 16 + l16] : 0.f;
    }
    float plv[2][4], prv[2][4];
#pragma unroll
    for (int rr = 0; rr < 2; rr++)
#pragma unroll
        for (int i = 0; i < 4; i++) {
            float pl = 0.f, pr = 0.f;
#pragma unroll
            for (int c = 0; c < 4; c++) {
                pl += acc[rr][c][i] * alv[c];
                pr += acc[rr][c][i] * arv[c];
            }
#pragma unroll
            for (int off = 1; off < 16; off <<= 1) {
                pl += __shfl_xor(pl, off);
                pr += __shfl_xor(pr, off);
            }
            plv[rr][i] = pl; prv[rr][i] = pr;
        }
    float* part = (float*)&BsF[0][0];      // [128][2] partials (wc=0 half)
    if (wc == 0 && l16 == 0) {
#pragma unroll
        for (int rr = 0; rr < 2; rr++)
#pragma unroll
            for (int i = 0; i < 4; i++) {
                int lr = wr * 32 + rr * 16 + quad * 4 + i;
                part[lr * 2 + 0] = plv[rr][i];
                part[lr * 2 + 1] = prv[rr][i];
            }
    }
    __syncthreads();                       // cs + part visible to all waves
    // ---- coalesced C store: each wave reads back 16 rows ----
    {
        short* Cs = (short*)C;
#pragma unroll
        for (int j = 0; j < 4; j++) {
            int lr = wave * 16 + j * 4 + (lane >> 4);
            int cc = lane & 15;
            int chunk = (cc + 2 * (lr >> 2)) & 15;
            v8s val = *(const v8s*)&cs[lr * 128 + (chunk << 3)];
            *(v8s*)&Cs[(size_t)(bm + lr) * N + bn + cc * 8] = val;
        }
    }
    // ---- wc=1 combines halves and stores logits ----
    if (wc == 1 && l16 == 0) {
#pragma unroll
        for (int rr = 0; rr < 2; rr++)
#pragma unroll
            for (int i = 0; i < 4; i++) {
                int lr = wr * 32 + rr * 16 + quad * 4 + i;
                float pl = part[lr * 2 + 0] + plv[rr][i];
                float pr = part[lr * 2 + 1] + prv[rr][i];
                int row = bm + lr;
                elp[(size_t)row * 4 + hh] = pl;
                if (erp) erp[(size_t)row * 4 + hh] = pr;
            }
    }
}

// ---------- fused CSR build, BOTH relations per dispatch ----------
__global__ void hist2(const int* __restrict__ dst_w, const int* __restrict__ dst_d,
                      int* __restrict__ deg_w, int* __restrict__ deg_d) {
    int t = blockIdx.x * blockDim.x + threadIdx.x;
    if (t < EWW) atomicAdd(&deg_w[dst_w[t]], 1);
    if (t < EWD) atomicAdd(&deg_d[dst_d[t]], 1);
}

__global__ __launch_bounds__(256) void scan_block2(
        const int* __restrict__ deg_w, int* __restrict__ rp_w, int* __restrict__ bsum_w,
        const int* __restrict__ deg_d, int* __restrict__ rp_d, int* __restrict__ bsum_d,
        int nbw) {
    const int* deg; int *rp, *bsum; int N, b;
    if ((int)blockIdx.x < nbw) { deg = deg_w; rp = rp_w; bsum = bsum_w; N = NW; b = blockIdx.x; }
    else { deg = deg_d; rp = rp_d; bsum = bsum_d; N = ND; b = blockIdx.x - nbw; }
    __shared__ int ts[256];
    int tid = threadIdx.x;
    int base = b * 1024 + tid * 4;
    int v0 = 0, v1 = 0, v2 = 0, v3 = 0;
    if (base + 3 < N) {
        int4 q = *(const int4*)(deg + base);
        v0 = q.x; v1 = q.y; v2 = q.z; v3 = q.w;
    } else {
        if (base + 0 < N) v0 = deg[base + 0];
        if (base + 1 < N) v1 = deg[base + 1];
        if (base + 2 < N) v2 = deg[base + 2];
        if (base + 3 < N) v3 = deg[base + 3];
    }
    int s = v0 + v1 + v2 + v3;
    ts[tid] = s;
    __syncthreads();
    for (int off = 1; off < 256; off <<= 1) {
        int t = (tid >= off) ? ts[tid - off] : 0;
        __syncthreads();
        ts[tid] += t;
        __syncthreads();
    }
    int excl = ts[tid] - s;
    if (tid == 255) bsum[b] = ts[255];
    if (base + 0 < N) rp[base + 0] = excl;
    if (base + 1 < N) rp[base + 1] = excl + v0;
    if (base + 2 < N) rp[base + 2] = excl + v0 + v1;
    if (base + 3 < N) rp[base + 3] = excl + v0 + v1 + v2;
}

// add_off with in-block bsum prefix (bsum arrays are tiny: 79 / 16 entries)
__global__ __launch_bounds__(256) void add_off2p(
        int* __restrict__ rp_w, const int* __restrict__ bsum_w, int nbw_s,
        int* __restrict__ rp_d, const int* __restrict__ bsum_d, int nbd_s) {
    int *rp; const int* bsum; int N, E, b, nb;
    if ((int)blockIdx.x < nbw_s) { rp = rp_w; bsum = bsum_w; N = NW; E = EWW; b = blockIdx.x; nb = nbw_s; }
    else { rp = rp_d; bsum = bsum_d; N = ND; E = EWD; b = blockIdx.x - nbw_s; nb = nbd_s; }
    __shared__ int ts[256];
    int tid = threadIdx.x;
    ts[tid] = (tid < b && tid < nb) ? bsum[tid] : 0;   // sum of blocks before b
    __syncthreads();
    for (int off = 128; off; off >>= 1) {
        if (tid < off) ts[tid] += ts[tid + off];
        __syncthreads();
    }
    int o = ts[0];
    int base = b * 1024 + tid * 4;
    if (base + 3 < N) {
        int4 q = *(const int4*)(rp + base);
        q.x += o; q.y += o; q.z += o; q.w += o;
        *(int4*)(rp + base) = q;
    } else {
        if (base + 0 < N) rp[base + 0] += o;
        if (base + 1 < N) rp[base + 1] += o;
        if (base + 2 < N) rp[base + 2] += o;
        if (base + 3 < N) rp[base + 3] += o;
    }
    if (b == 0 && tid == 0) rp[N] = E;
}

__global__ void scatter2(const int* __restrict__ src_w, const int* __restrict__ dst_w,
                         const int* __restrict__ rp_w, int* __restrict__ cnt_w,
                         int* __restrict__ ss_w,
                         const int* __restrict__ src_d, const int* __restrict__ dst_d,
                         const int* __restrict__ rp_d, int* __restrict__ cnt_d,
                         int* __restrict__ ss_d) {
    int t = blockIdx.x * blockDim.x + threadIdx.x;
    if (t < EWW) {
        int d = dst_w[t];
        int pos = rp_w[d] + atomicAdd(&cnt_w[d], 1);
        ss_w[pos] = src_w[t];
    }
    if (t < EWD) {
        int d = dst_d[t];
        int pos = rp_d[d] + atomicAdd(&cnt_d[d], 1);
        ss_d[pos] = src_d[t];
    }
}

// ---------- fused edge-softmax + aggregate, BOTH relations in one dispatch ----------
__global__ __launch_bounds__(256) void softmax_agg2(
        const int* __restrict__ rp_w, const int* __restrict__ ss_w,
        const float* __restrict__ el_w, const float* __restrict__ er_w,
        const float* __restrict__ b_w,
        const int* __restrict__ rp_d, const int* __restrict__ ss_d,
        const float* __restrict__ el_d, const float* __restrict__ er_d,
        const float* __restrict__ b_d,
        const __hip_bfloat16* __restrict__ z,
        float* __restrict__ outf_w, __hip_bfloat16* __restrict__ outb_w,
        float* __restrict__ outf_d, __hip_bfloat16* __restrict__ outb_d,
        int nbw) {
    int wave = threadIdx.x >> 6, lane = threadIdx.x & 63;
    int h0 = lane >> 4, l16 = lane & 15;
    const int *rp, *ss;
    const float *el, *er, *bv;
    float* outf;
    __hip_bfloat16* outb;
    int d, Nd, zoff;
    if ((int)blockIdx.x < nbw) {
        rp = rp_w; ss = ss_w; el = el_w; er = er_w; bv = b_w;
        outf = outf_w; outb = outb_w; zoff = 0; Nd = NW;
        d = blockIdx.x * 4 + wave;
    } else {
        rp = rp_d; ss = ss_d; el = el_d; er = er_d; bv = b_d;
        outf = outf_d; outb = outb_d; zoff = 512; Nd = ND;
        d = (blockIdx.x - nbw) * 4 + wave;
    }
    if (d >= Nd) return;
    int i0 = rp[d], i1 = rp[d + 1];
    float er_own = er[(size_t)d * 4 + h0];
    float bb[8];
#pragma unroll
    for (int t = 0; t < 8; t++) bb[t] = bv[h0 * 128 + l16 * 8 + t];

    float m = -FLT_MAX, l = 0.f;
    float acc[8];
#pragma unroll
    for (int t = 0; t < 8; t++) acc[t] = 0.f;

    const __hip_bfloat16* zb = z + zoff;
    auto PROC = [&](float elv, const uint4& zv) {
        float e = elv + er_own;
        e = e > 0.f ? e : 0.2f * e;                 // leaky_relu(0.2)
        float nm = fmaxf(m, e);
        float sc = __expf(m - nm);
        float p  = __expf(e - nm);
        m = nm;
        l = l * sc + p;
        acc[0] = acc[0] * sc + p * blo(zv.x);
        acc[1] = acc[1] * sc + p * bhi(zv.x);
        acc[2] = acc[2] * sc + p * blo(zv.y);
        acc[3] = acc[3] * sc + p * bhi(zv.y);
        acc[4] = acc[4] * sc + p * blo(zv.z);
        acc[5] = acc[5] * sc + p * bhi(zv.z);
        acc[6] = acc[6] * sc + p * blo(zv.w);
        acc[7] = acc[7] * sc + p * bhi(zv.w);
    };

    if (i0 < i1) {
        int last = i1 - 1;
        int s0 = ss[i0];
        int s1 = ss[min(i0 + 1, last)];
        int s2 = ss[min(i0 + 2, last)];
        int s3 = ss[min(i0 + 3, last)];
        for (int i = i0; i < i1; i += 4) {
            float e0 = el[(size_t)s0 * 4 + h0];
            float e1 = el[(size_t)s1 * 4 + h0];
            float e2 = el[(size_t)s2 * 4 + h0];
            float e3 = el[(size_t)s3 * 4 + h0];
            uint4 z0 = ((const uint4*)(zb + (size_t)s0 * 1024))[lane];
            uint4 z1 = ((const uint4*)(zb + (size_t)s1 * 1024))[lane];
            uint4 z2 = ((const uint4*)(zb + (size_t)s2 * 1024))[lane];
            uint4 z3 = ((const uint4*)(zb + (size_t)s3 * 1024))[lane];
            s0 = ss[min(i + 4, last)];
            s1 = ss[min(i + 5, last)];
            s2 = ss[min(i + 6, last)];
            s3 = ss[min(i + 7, last)];
            int rem = i1 - i;
            PROC(e0, z0);
            if (rem > 1) PROC(e1, z1);
            if (rem > 2) PROC(e2, z2);
            if (rem > 3) PROC(e3, z3);
        }
    }

    float inv = l > 0.f ? 1.f / l : 0.f;
    float v[8];
#pragma unroll
    for (int t = 0; t < 8; t++) v[t] = acc[t] * inv + bb[t];
#pragma unroll
    for (int t = 0; t < 8; t++) {
        v[t] += __shfl_xor(v[t], 16);
        v[t] += __shfl_xor(v[t], 32);
    }
#pragma unroll
    for (int t = 0; t < 8; t++) v[t] = fmaxf(v[t], 0.f);   // relu
    if (lane < 16) {
        if (outf) {
            float4 o0 = make_float4(v[0], v[1], v[2], v[3]);
            float4 o1 = make_float4(v[4], v[5], v[6], v[7]);
            *(float4*)(outf + (size_t)d * 128 + l16 * 8)     = o0;
            *(float4*)(outf + (size_t)d * 128 + l16 * 8 + 4) = o1;
        } else {
            __hip_bfloat162 p01, p23, p45, p67;
            p01.x = __float2bfloat16(v[0]); p01.y = __float2bfloat16(v[1]);
            p23.x = __float2bfloat16(v[2]); p23.y = __float2bfloat16(v[3]);
            p45.x = __float2bfloat16(v[4]); p45.y = __float2bfloat16(v[5]);
            p67.x = __float2bfloat16(v[6]); p67.y = __float2bfloat16(v[7]);
            uint4 o;
            o.x = *(unsigned*)&p01; o.y = *(unsigned*)&p23;
            o.z = *(unsigned*)&p45; o.w = *(unsigned*)&p67;
            *(uint4*)(outb + (size_t)d * 128 + l16 * 8) = o;
        }
    }
}

static inline char* aln(char*& p, size_t bytes) {
    char* r = p;
    p += (bytes + 255) & ~(size_t)255;
    return r;
}

extern "C" void kernel_launch(void* const* d_in, const int* in_sizes, int n_in,
                              void* d_out, int out_size, void* d_ws, size_t ws_size,
                              hipStream_t stream) {
    const float* xw     = (const float*)d_in[0];
    const float* xd     = (const float*)d_in[1];
    const float* W_ww0  = (const float*)d_in[2];
    const float* al_ww0 = (const float*)d_in[3];
    const float* ar_ww0 = (const float*)d_in[4];
    const float* b_ww0  = (const float*)d_in[5];
    const float* W_wd0  = (const float*)d_in[6];
    const float* al_wd0 = (const float*)d_in[7];
    const float* ar_wd0 = (const float*)d_in[8];
    const float* b_wd0  = (const float*)d_in[9];
    const float* W_ww1  = (const float*)d_in[10];
    const float* al_ww1 = (const float*)d_in[11];
    const float* ar_ww1 = (const float*)d_in[12];
    const float* b_ww1  = (const float*)d_in[13];
    const float* W_wd1  = (const float*)d_in[14];
    const float* al_wd1 = (const float*)d_in[15];
    const float* ar_wd1 = (const float*)d_in[16];
    const float* b_wd1  = (const float*)d_in[17];
    const int* ww_src   = (const int*)d_in[18];
    const int* ww_dst   = (const int*)d_in[19];
    const int* wd_src   = (const int*)d_in[20];
    const int* wd_dst   = (const int*)d_in[21];

    // ---- workspace carve ----
    char* p = (char*)d_ws;
    __hip_bfloat16* z    = (__hip_bfloat16*)aln(p, (size_t)NW * 1024 * 2);  // 164 MB
    __hip_bfloat16* xwb  = (__hip_bfloat16*)aln(p, (size_t)NW * 256 * 2);
    __hip_bfloat16* xw1b = (__hip_bfloat16*)aln(p, (size_t)NW * 128 * 2);
    __hip_bfloat16* xd1b = (__hip_bfloat16*)aln(p, (size_t)ND * 128 * 2);
    __hip_bfloat16* Wt0  = (__hip_bfloat16*)aln(p, (size_t)1024 * 256 * 2);
    __hip_bfloat16* Wt1  = (__hip_bfloat16*)aln(p, (size_t)1024 * 128 * 2);
    float* el0  = (float*)aln(p, (size_t)NW * 4 * 4);
    float* er0  = (float*)aln(p, (size_t)NW * 4 * 4);
    float* el1  = (float*)aln(p, (size_t)NW * 4 * 4);
    float* er1  = (float*)aln(p, (size_t)ND * 4 * 4);
    float* Wr0  = (float*)aln(p, 4096);
    float* Wr1  = (float*)aln(p, 4096);
    // deg arrays: NW*2*4 = 640000 B (256-aligned) then ND*2*4 — contiguous
    int* deg_ww = (int*)aln(p, (size_t)NW * 2 * 4);
    int* deg_wd = (int*)aln(p, (size_t)ND * 2 * 4);
    int* rp_ww  = (int*)aln(p, (size_t)(NW + 1) * 4);
    int* ss_ww  = (int*)aln(p, (size_t)EWW * 4);
    int* rp_wd  = (int*)aln(p, (size_t)(ND + 1) * 4);
    int* ss_wd  = (int*)aln(p, (size_t)EWD * 4);
    int* bsum   = (int*)aln(p, 2048);
    int* bsum_w = bsum;
    int* bsum_d = bsum + 256;

    float* out_xw = (float*)d_out;
    float* out_xd = out_xw + (size_t)NW * 128;

    const int NBW_S = (NW + 1023) / 1024;   // 79
    const int NBD_S = (ND + 1023) / 1024;   // 16

    // ---- fused: cast + weight prep + deg zeroing (one dispatch) ----
    util_all<<<21730, 256, 0, stream>>>((const float4*)xw, (uint2*)xwb,
                                        W_ww0, W_wd0, W_ww1, W_wd1, ar_wd0, ar_wd1,
                                        Wt0, Wt1, Wr0, Wr1, (int4*)deg_ww);

    // ---- fused CSR build ----
    hist2<<<(EWW + 255) / 256, 256, 0, stream>>>(ww_dst, wd_dst, deg_ww, deg_wd);
    scan_block2<<<NBW_S + NBD_S, 256, 0, stream>>>(deg_ww, rp_ww, bsum_w,
                                                   deg_wd, rp_wd, bsum_d, NBW_S);
    add_off2p<<<NBW_S + NBD_S, 256, 0, stream>>>(rp_ww, bsum_w, NBW_S, rp_wd, bsum_d, NBD_S);
    scatter2<<<(EWW + 255) / 256, 256, 0, stream>>>(ww_src, ww_dst, rp_ww, deg_ww + NW, ss_ww,
                                                    wd_src, wd_dst, rp_wd, deg_wd + ND, ss_wd);

    const int GEMM_BLOCKS = 8 * (NW / 128);   // 5000
    const int ATT_BLOCKS = (ND + 7) / 8;      // 2000
    const int NBW = (NW + 3) / 4, NBD = (ND + 3) / 4;

    // ================= layer 0 (K=256) =================
    gemm_epi<<<GEMM_BLOCKS + ATT_BLOCKS, 512, 0, stream>>>(
        xwb, Wt0, z, al_ww0, ar_ww0, al_wd0, el0, er0, el1, NW, 256,
        xd, nullptr, Wr0, er1, ND);
    softmax_agg2<<<NBW + NBD, 256, 0, stream>>>(
        rp_ww, ss_ww, el0, er0, b_ww0,
        rp_wd, ss_wd, el1, er1, b_wd0,
        z, nullptr, xw1b, nullptr, xd1b, NBW);

    // ================= layer 1 (K=128) =================
    gemm_epi<<<GEMM_BLOCKS + ATT_BLOCKS, 512, 0, stream>>>(
        xw1b, Wt1, z, al_ww1, ar_ww1, al_wd1, el0, er0, el1, NW, 128,
        nullptr, xd1b, Wr1, er1, ND);
    softmax_agg2<<<NBW + NBD, 256, 0, stream>>>(
        rp_ww, ss_ww, el0, er0, b_ww1,
        rp_wd, ss_wd, el1, er1, b_wd1,
        z, out_xw, nullptr, out_xd, nullptr, NBW);
}

// Round 7
// 507.285 us; speedup vs baseline: 1.0633x; 1.0633x over previous
//
#include <hip/hip_runtime.h>
#include <hip/hip_bf16.h>
#include <cstddef>
#include <cfloat>

#define NW 80000
#define ND 16000
#define EWW 200000
#define EWD 200000

typedef short v8s __attribute__((ext_vector_type(8)));
typedef float v4f __attribute__((ext_vector_type(4)));

static __device__ __forceinline__ float blo(unsigned u) { return __uint_as_float(u << 16); }
static __device__ __forceinline__ float bhi(unsigned u) { return __uint_as_float(u & 0xffff0000u); }

// async global->LDS 16B copy: lane i of the wave writes lds_base + i*16
static __device__ __forceinline__ void gl2lds16(const void* g, void* l) {
    __builtin_amdgcn_global_load_lds((__attribute__((address_space(1))) void*)g,
                                     (__attribute__((address_space(3))) void*)l, 16, 0, 0);
}

// ---------- fused utility dispatch: cast + weight prep (both layers) + deg zeroing ----
// blocks [0,20000): cast xw fp32->bf16 (x4)
// [20000,21024): transpose L0 -> Wt0 ; [21024,21536): transpose L1 -> Wt1
// [21536,21540): make_wr L0 ; [21540,21542): make_wr L1
// [21542,21730): zero deg arrays (contiguous int4 region)
__global__ __launch_bounds__(256) void util_all(
        const float4* __restrict__ xw4, uint2* __restrict__ xwb,
        const float* __restrict__ W_ww0, const float* __restrict__ W_wd0,
        const float* __restrict__ W_ww1, const float* __restrict__ W_wd1,
        const float* __restrict__ ar_wd0, const float* __restrict__ ar_wd1,
        __hip_bfloat16* __restrict__ Wt0, __hip_bfloat16* __restrict__ Wt1,
        float* __restrict__ Wr0, float* __restrict__ Wr1,
        int4* __restrict__ degz) {
    int bid = blockIdx.x, tid = threadIdx.x;
    if (bid < 20000) {
        int i = bid * 256 + tid;                 // 5,120,000 exactly
        float4 v = xw4[i];
        __hip_bfloat162 a, b;
        a.x = __float2bfloat16(v.x); a.y = __float2bfloat16(v.y);
        b.x = __float2bfloat16(v.z); b.y = __float2bfloat16(v.w);
        uint2 o;
        o.x = *(unsigned*)&a; o.y = *(unsigned*)&b;
        xwb[i] = o;
    } else if (bid < 21024) {
        int i = (bid - 20000) * 256 + tid;       // 1024*256, K=256
        int n = i >> 8, k = i & 255;
        float v = (n < 512) ? W_ww0[k * 512 + n] : W_wd0[k * 512 + (n - 512)];
        Wt0[n * 256 + k] = __float2bfloat16(v);
    } else if (bid < 21536) {
        int i = (bid - 21024) * 256 + tid;       // 1024*128, K=128
        int n = i >> 7, k = i & 127;
        float v = (n < 512) ? W_ww1[k * 512 + n] : W_wd1[k * 512 + (n - 512)];
        Wt1[n * 128 + k] = __float2bfloat16(v);
    } else if (bid < 21540) {
        int i = (bid - 21536) * 256 + tid;       // 256*4
        int k = i >> 2, h = i & 3;
        float sr = 0.f;
        const float* wr = W_wd0 + (size_t)k * 512 + h * 128;
        const float* arr = ar_wd0 + h * 128;
        for (int f = 0; f < 128; f++) sr += wr[f] * arr[f];
        Wr0[k * 4 + h] = sr;
    } else if (bid < 21542) {
        int i = (bid - 21540) * 256 + tid;       // 128*4
        int k = i >> 2, h = i & 3;
        float sr = 0.f;
        const float* wr = W_wd1 + (size_t)k * 512 + h * 128;
        const float* arr = ar_wd1 + h * 128;
        for (int f = 0; f < 128; f++) sr += wr[f] * arr[f];
        Wr1[k * 4 + h] = sr;
    } else {
        int idx = (bid - 21542) * 256 + tid;     // 48000 int4 = 192000 ints
        if (idx < 48000) degz[idx] = make_int4(0, 0, 0, 0);
    }
}

// ---------- merged bf16 MFMA GEMM (both relations) + attention-logit epilogue ----------
// z[M,1024] = A[M,K] @ [W_ww | W_wd]  (Bt = concat^T [1024,K]).  BM=128, BK=64.
// EXACT r5-measured structure (95.8us): 8 waves x 16 rows, T3+T4 counted-vmcnt
// pipeline, T5 setprio, rotated-chunk LDS writeback (conflict-free), wave-private
// slabs (no extra barrier). r6's 4x2 grid + in-dispatch attn GEMV regressed to
// 120us (LDS-capped GEMV tail) — reverted.
__global__ __launch_bounds__(512) void gemm_epi(const __hip_bfloat16* __restrict__ A,
                                                const __hip_bfloat16* __restrict__ Bt,
                                                __hip_bfloat16* __restrict__ C,
                                                const float* __restrict__ al0,
                                                const float* __restrict__ ar0,
                                                const float* __restrict__ al1,
                                                float* __restrict__ el0,
                                                float* __restrict__ er0,
                                                float* __restrict__ el1,
                                                int M, int K) {
    const int N = 1024;
    __shared__ short AsF[2][128 * 64];   // 2 x 16 KB, row stride 64 shorts
    __shared__ short BsF[2][128 * 64];
    int tid = threadIdx.x;
    int wave = tid >> 6, lane = tid & 63;    // wave 0..7, 16 rows each
    int l16 = lane & 15, quad = lane >> 4;

    // ---- XCD swizzle ----
    int MT = M >> 7;
    int full = MT >> 3;
    int bid = blockIdx.x;
    int h, mt;
    if (bid < (full << 6)) {
        int s = bid >> 6, r = bid & 63;
        h = r >> 3;
        mt = (s << 3) | (r & 7);
    } else {
        int r2 = bid - (full << 6);
        int rem = MT - (full << 3);
        h = r2 / rem;
        mt = (full << 3) + (r2 - h * rem);
    }
    bool isww = h < 4;
    int hh = isww ? h : h - 4;
    int bm = mt * 128, bn = h * 128;
    v4f acc[8] = {};

    int laneR = lane >> 3;                 // 0..7
    int laneC = (lane & 7) ^ laneR;        // swizzled 16B-chunk index
    const __hip_bfloat16* ga = A  + (size_t)(bm + wave * 16 + laneR) * K + laneC * 8;
    const __hip_bfloat16* gb = Bt + (size_t)(bn + wave * 16 + laneR) * K + laneC * 8;
    int lofs = (wave * 16) * 64;           // short offset of this wave's 16-row slab

    auto STAGE = [&](int buf, int k0) {
#pragma unroll
        for (int j = 0; j < 2; j++) {
            gl2lds16(ga + (size_t)(j * 8) * K + k0, &AsF[buf][lofs + j * 512]);
            gl2lds16(gb + (size_t)(j * 8) * K + k0, &BsF[buf][lofs + j * 512]);
        }
    };
    auto COMPUTE = [&](int buf) {
#pragma unroll
        for (int kh = 0; kh < 2; kh++) {
            int s = (kh * 4 + quad) ^ (l16 & 7);
            v8s a0, b[8];
            a0 = *(const v8s*)&AsF[buf][(wave * 16 + l16) * 64 + s * 8];
#pragma unroll
            for (int c = 0; c < 8; c++)
                b[c] = *(const v8s*)&BsF[buf][(c * 16 + l16) * 64 + s * 8];
            __builtin_amdgcn_s_setprio(1);
#pragma unroll
            for (int c = 0; c < 8; c++)
                acc[c] = __builtin_amdgcn_mfma_f32_16x16x32_bf16(a0, b[c], acc[c], 0, 0, 0);
            __builtin_amdgcn_s_setprio(0);
        }
    };

    STAGE(0, 0);
    for (int k0 = 0; k0 < K; k0 += 128) {
        if (k0 + 64 < K) {
            STAGE(1, k0 + 64);
            asm volatile("s_waitcnt vmcnt(4)" ::: "memory");
        } else {
            asm volatile("s_waitcnt vmcnt(0)" ::: "memory");
        }
        __builtin_amdgcn_s_barrier();
        asm volatile("" ::: "memory");
        COMPUTE(0);
        __builtin_amdgcn_s_barrier();
        asm volatile("" ::: "memory");
        if (k0 + 128 < K) {
            STAGE(0, k0 + 128);
            asm volatile("s_waitcnt vmcnt(4)" ::: "memory");
        } else {
            asm volatile("s_waitcnt vmcnt(0)" ::: "memory");
        }
        __builtin_amdgcn_s_barrier();
        asm volatile("" ::: "memory");
        COMPUTE(1);
        __builtin_amdgcn_s_barrier();
        asm volatile("" ::: "memory");
    }

    // ---- C writeback via LDS re-stage (wave-private 16-row slabs) ----
    short* cs = &AsF[0][0];                  // flat 32KB = [128][128] bf16, rotated chunks
#pragma unroll
    for (int c = 0; c < 8; c++)
#pragma unroll
        for (int i = 0; i < 4; i++) {
            int lr = wave * 16 + quad * 4 + i;
            int sIdx = c * 16 + l16;
            int chunk = ((sIdx >> 3) + 2 * (lr >> 2)) & 15;   // rotate per 4-row group
            cs[lr * 128 + (chunk << 3) + (sIdx & 7)] =
                (short)__bfloat16_as_ushort(__float2bfloat16(acc[c][i]));
        }
    {
        short* Cs = (short*)C;
#pragma unroll
        for (int j = 0; j < 4; j++) {
            int lr = wave * 16 + j * 4 + (lane >> 4);     // local row
            int cc = lane & 15;                           // logical 16B chunk
            int chunk = (cc + 2 * (lr >> 2)) & 15;        // physical chunk
            v8s val = *(const v8s*)&cs[lr * 128 + (chunk << 3)];
            *(v8s*)&Cs[(size_t)(bm + lr) * N + bn + cc * 8] = val;
        }
    }
    // epilogue: el (and er for ww heads) via per-lane dot + 16-lane shuffle reduce
    const float* alp = isww ? al0 : al1;
    float* elp = isww ? el0 : el1;
    float* erp = isww ? er0 : nullptr;
    float alv[8], arv[8];
#pragma unroll
    for (int c = 0; c < 8; c++) {
        alv[c] = alp[hh * 128 + c * 16 + l16];
        arv[c] = isww ? ar0[hh * 128 + c * 16 + l16] : 0.f;
    }
#pragma unroll
    for (int i = 0; i < 4; i++) {
        float pl = 0.f, pr = 0.f;
#pragma unroll
        for (int c = 0; c < 8; c++) {
            pl += acc[c][i] * alv[c];
            pr += acc[c][i] * arv[c];
        }
#pragma unroll
        for (int off = 1; off < 16; off <<= 1) {
            pl += __shfl_xor(pl, off);
            pr += __shfl_xor(pr, off);
        }
        if (l16 == 0) {
            int row = bm + wave * 16 + quad * 4 + i;
            elp[(size_t)row * 4 + hh] = pl;
            if (erp) erp[(size_t)row * 4 + hh] = pr;
        }
    }
}

// ---------- fused CSR build, BOTH relations per dispatch ----------
__global__ void hist2(const int* __restrict__ dst_w, const int* __restrict__ dst_d,
                      int* __restrict__ deg_w, int* __restrict__ deg_d) {
    int t = blockIdx.x * blockDim.x + threadIdx.x;
    if (t < EWW) atomicAdd(&deg_w[dst_w[t]], 1);
    if (t < EWD) atomicAdd(&deg_d[dst_d[t]], 1);
}

__global__ __launch_bounds__(256) void scan_block2(
        const int* __restrict__ deg_w, int* __restrict__ rp_w, int* __restrict__ bsum_w,
        const int* __restrict__ deg_d, int* __restrict__ rp_d, int* __restrict__ bsum_d,
        int nbw) {
    const int* deg; int *rp, *bsum; int N, b;
    if ((int)blockIdx.x < nbw) { deg = deg_w; rp = rp_w; bsum = bsum_w; N = NW; b = blockIdx.x; }
    else { deg = deg_d; rp = rp_d; bsum = bsum_d; N = ND; b = blockIdx.x - nbw; }
    __shared__ int ts[256];
    int tid = threadIdx.x;
    int base = b * 1024 + tid * 4;
    int v0 = 0, v1 = 0, v2 = 0, v3 = 0;
    if (base + 3 < N) {
        int4 q = *(const int4*)(deg + base);
        v0 = q.x; v1 = q.y; v2 = q.z; v3 = q.w;
    } else {
        if (base + 0 < N) v0 = deg[base + 0];
        if (base + 1 < N) v1 = deg[base + 1];
        if (base + 2 < N) v2 = deg[base + 2];
        if (base + 3 < N) v3 = deg[base + 3];
    }
    int s = v0 + v1 + v2 + v3;
    ts[tid] = s;
    __syncthreads();
    for (int off = 1; off < 256; off <<= 1) {
        int t = (tid >= off) ? ts[tid - off] : 0;
        __syncthreads();
        ts[tid] += t;
        __syncthreads();
    }
    int excl = ts[tid] - s;
    if (tid == 255) bsum[b] = ts[255];
    if (base + 0 < N) rp[base + 0] = excl;
    if (base + 1 < N) rp[base + 1] = excl + v0;
    if (base + 2 < N) rp[base + 2] = excl + v0 + v1;
    if (base + 3 < N) rp[base + 3] = excl + v0 + v1 + v2;
}

// add_off with in-block bsum prefix (bsum arrays are tiny: 79 / 16 entries)
__global__ __launch_bounds__(256) void add_off2p(
        int* __restrict__ rp_w, const int* __restrict__ bsum_w, int nbw_s,
        int* __restrict__ rp_d, const int* __restrict__ bsum_d, int nbd_s) {
    int *rp; const int* bsum; int N, E, b, nb;
    if ((int)blockIdx.x < nbw_s) { rp = rp_w; bsum = bsum_w; N = NW; E = EWW; b = blockIdx.x; nb = nbw_s; }
    else { rp = rp_d; bsum = bsum_d; N = ND; E = EWD; b = blockIdx.x - nbw_s; nb = nbd_s; }
    __shared__ int ts[256];
    int tid = threadIdx.x;
    ts[tid] = (tid < b && tid < nb) ? bsum[tid] : 0;   // sum of blocks before b
    __syncthreads();
    for (int off = 128; off; off >>= 1) {
        if (tid < off) ts[tid] += ts[tid + off];
        __syncthreads();
    }
    int o = ts[0];
    int base = b * 1024 + tid * 4;
    if (base + 3 < N) {
        int4 q = *(const int4*)(rp + base);
        q.x += o; q.y += o; q.z += o; q.w += o;
        *(int4*)(rp + base) = q;
    } else {
        if (base + 0 < N) rp[base + 0] += o;
        if (base + 1 < N) rp[base + 1] += o;
        if (base + 2 < N) rp[base + 2] += o;
        if (base + 3 < N) rp[base + 3] += o;
    }
    if (b == 0 && tid == 0) rp[N] = E;
}

__global__ void scatter2(const int* __restrict__ src_w, const int* __restrict__ dst_w,
                         const int* __restrict__ rp_w, int* __restrict__ cnt_w,
                         int* __restrict__ ss_w,
                         const int* __restrict__ src_d, const int* __restrict__ dst_d,
                         const int* __restrict__ rp_d, int* __restrict__ cnt_d,
                         int* __restrict__ ss_d) {
    int t = blockIdx.x * blockDim.x + threadIdx.x;
    if (t < EWW) {
        int d = dst_w[t];
        int pos = rp_w[d] + atomicAdd(&cnt_w[d], 1);
        ss_w[pos] = src_w[t];
    }
    if (t < EWD) {
        int d = dst_d[t];
        int pos = rp_d[d] + atomicAdd(&cnt_d[d], 1);
        ss_d[pos] = src_d[t];
    }
}

// ---------- fused edge-softmax + aggregate, BOTH relations in one dispatch ----------
// wd-side blocks also compute their own dst's er logits in a per-wave prologue
// (vectorized row read + 6-step shfl_xor butterfly; all lanes get all 4 head sums,
// each keeps its own head) — removes the separate attn GEMV dispatches entirely.
__global__ __launch_bounds__(256) void softmax_agg2(
        const int* __restrict__ rp_w, const int* __restrict__ ss_w,
        const float* __restrict__ el_w, const float* __restrict__ er_w,
        const float* __restrict__ b_w,
        const int* __restrict__ rp_d, const int* __restrict__ ss_d,
        const float* __restrict__ el_d, const float* __restrict__ b_d,
        const float* __restrict__ xd_f, const __hip_bfloat16* __restrict__ xd_b,
        const float* __restrict__ Wv,
        const __hip_bfloat16* __restrict__ z,
        float* __restrict__ outf_w, __hip_bfloat16* __restrict__ outb_w,
        float* __restrict__ outf_d, __hip_bfloat16* __restrict__ outb_d,
        int nbw) {
    int wave = threadIdx.x >> 6, lane = threadIdx.x & 63;
    int h0 = lane >> 4, l16 = lane & 15;
    const int *rp, *ss;
    const float *el, *bv;
    float* outf;
    __hip_bfloat16* outb;
    int d, Nd, zoff;
    bool isdoc = (int)blockIdx.x >= nbw;
    if (!isdoc) {
        rp = rp_w; ss = ss_w; el = el_w; bv = b_w;
        outf = outf_w; outb = outb_w; zoff = 0; Nd = NW;
        d = blockIdx.x * 4 + wave;
    } else {
        rp = rp_d; ss = ss_d; el = el_d; bv = b_d;
        outf = outf_d; outb = outb_d; zoff = 512; Nd = ND;
        d = (blockIdx.x - nbw) * 4 + wave;
    }
    if (d >= Nd) return;

    float er_own;
    if (!isdoc) {
        er_own = er_w[(size_t)d * 4 + h0];
    } else {
        // ---- in-kernel er GEMV for this doc row ----
        float a0 = 0.f, a1 = 0.f, a2 = 0.f, a3 = 0.f;
        const float4* Wv4 = (const float4*)Wv;     // [K] heads-vector per k
        if (xd_f) {
            // layer 0: K=256 fp32; lane covers k = lane*4 .. lane*4+3
            float4 xv = ((const float4*)(xd_f + (size_t)d * 256))[lane];
            float4 w0 = Wv4[lane * 4 + 0], w1 = Wv4[lane * 4 + 1];
            float4 w2 = Wv4[lane * 4 + 2], w3 = Wv4[lane * 4 + 3];
            a0 = xv.x * w0.x + xv.y * w1.x + xv.z * w2.x + xv.w * w3.x;
            a1 = xv.x * w0.y + xv.y * w1.y + xv.z * w2.y + xv.w * w3.y;
            a2 = xv.x * w0.z + xv.y * w1.z + xv.z * w2.z + xv.w * w3.z;
            a3 = xv.x * w0.w + xv.y * w1.w + xv.z * w2.w + xv.w * w3.w;
        } else {
            // layer 1: K=128 bf16; lane covers k = lane*2, lane*2+1
            unsigned u = ((const unsigned*)(xd_b + (size_t)d * 128))[lane];
            float x0 = blo(u), x1 = bhi(u);
            float4 w0 = Wv4[lane * 2 + 0], w1 = Wv4[lane * 2 + 1];
            a0 = x0 * w0.x + x1 * w1.x;
            a1 = x0 * w0.y + x1 * w1.y;
            a2 = x0 * w0.z + x1 * w1.z;
            a3 = x0 * w0.w + x1 * w1.w;
        }
#pragma unroll
        for (int off = 32; off; off >>= 1) {
            a0 += __shfl_xor(a0, off); a1 += __shfl_xor(a1, off);
            a2 += __shfl_xor(a2, off); a3 += __shfl_xor(a3, off);
        }
        er_own = (h0 == 0) ? a0 : (h0 == 1) ? a1 : (h0 == 2) ? a2 : a3;
    }

    int i0 = rp[d], i1 = rp[d + 1];
    float bb[8];
#pragma unroll
    for (int t = 0; t < 8; t++) bb[t] = bv[h0 * 128 + l16 * 8 + t];

    float m = -FLT_MAX, l = 0.f;
    float acc[8];
#pragma unroll
    for (int t = 0; t < 8; t++) acc[t] = 0.f;

    const __hip_bfloat16* zb = z + zoff;
    auto PROC = [&](float elv, const uint4& zv) {
        float e = elv + er_own;
        e = e > 0.f ? e : 0.2f * e;                 // leaky_relu(0.2)
        float nm = fmaxf(m, e);
        float sc = __expf(m - nm);
        float p  = __expf(e - nm);
        m = nm;
        l = l * sc + p;
        acc[0] = acc[0] * sc + p * blo(zv.x);
        acc[1] = acc[1] * sc + p * bhi(zv.x);
        acc[2] = acc[2] * sc + p * blo(zv.y);
        acc[3] = acc[3] * sc + p * bhi(zv.y);
        acc[4] = acc[4] * sc + p * blo(zv.z);
        acc[5] = acc[5] * sc + p * bhi(zv.z);
        acc[6] = acc[6] * sc + p * blo(zv.w);
        acc[7] = acc[7] * sc + p * bhi(zv.w);
    };

    if (i0 < i1) {
        int last = i1 - 1;
        int s0 = ss[i0];
        int s1 = ss[min(i0 + 1, last)];
        int s2 = ss[min(i0 + 2, last)];
        int s3 = ss[min(i0 + 3, last)];
        for (int i = i0; i < i1; i += 4) {
            float e0 = el[(size_t)s0 * 4 + h0];
            float e1 = el[(size_t)s1 * 4 + h0];
            float e2 = el[(size_t)s2 * 4 + h0];
            float e3 = el[(size_t)s3 * 4 + h0];
            uint4 z0 = ((const uint4*)(zb + (size_t)s0 * 1024))[lane];
            uint4 z1 = ((const uint4*)(zb + (size_t)s1 * 1024))[lane];
            uint4 z2 = ((const uint4*)(zb + (size_t)s2 * 1024))[lane];
            uint4 z3 = ((const uint4*)(zb + (size_t)s3 * 1024))[lane];
            s0 = ss[min(i + 4, last)];
            s1 = ss[min(i + 5, last)];
            s2 = ss[min(i + 6, last)];
            s3 = ss[min(i + 7, last)];
            int rem = i1 - i;
            PROC(e0, z0);
            if (rem > 1) PROC(e1, z1);
            if (rem > 2) PROC(e2, z2);
            if (rem > 3) PROC(e3, z3);
        }
    }

    float inv = l > 0.f ? 1.f / l : 0.f;
    float v[8];
#pragma unroll
    for (int t = 0; t < 8; t++) v[t] = acc[t] * inv + bb[t];
#pragma unroll
    for (int t = 0; t < 8; t++) {
        v[t] += __shfl_xor(v[t], 16);
        v[t] += __shfl_xor(v[t], 32);
    }
#pragma unroll
    for (int t = 0; t < 8; t++) v[t] = fmaxf(v[t], 0.f);   // relu
    if (lane < 16) {
        if (outf) {
            float4 o0 = make_float4(v[0], v[1], v[2], v[3]);
            float4 o1 = make_float4(v[4], v[5], v[6], v[7]);
            *(float4*)(outf + (size_t)d * 128 + l16 * 8)     = o0;
            *(float4*)(outf + (size_t)d * 128 + l16 * 8 + 4) = o1;
        } else {
            __hip_bfloat162 p01, p23, p45, p67;
            p01.x = __float2bfloat16(v[0]); p01.y = __float2bfloat16(v[1]);
            p23.x = __float2bfloat16(v[2]); p23.y = __float2bfloat16(v[3]);
            p45.x = __float2bfloat16(v[4]); p45.y = __float2bfloat16(v[5]);
            p67.x = __float2bfloat16(v[6]); p67.y = __float2bfloat16(v[7]);
            uint4 o;
            o.x = *(unsigned*)&p01; o.y = *(unsigned*)&p23;
            o.z = *(unsigned*)&p45; o.w = *(unsigned*)&p67;
            *(uint4*)(outb + (size_t)d * 128 + l16 * 8) = o;
        }
    }
}

static inline char* aln(char*& p, size_t bytes) {
    char* r = p;
    p += (bytes + 255) & ~(size_t)255;
    return r;
}

extern "C" void kernel_launch(void* const* d_in, const int* in_sizes, int n_in,
                              void* d_out, int out_size, void* d_ws, size_t ws_size,
                              hipStream_t stream) {
    const float* xw     = (const float*)d_in[0];
    const float* xd     = (const float*)d_in[1];
    const float* W_ww0  = (const float*)d_in[2];
    const float* al_ww0 = (const float*)d_in[3];
    const float* ar_ww0 = (const float*)d_in[4];
    const float* b_ww0  = (const float*)d_in[5];
    const float* W_wd0  = (const float*)d_in[6];
    const float* al_wd0 = (const float*)d_in[7];
    const float* ar_wd0 = (const float*)d_in[8];
    const float* b_wd0  = (const float*)d_in[9];
    const float* W_ww1  = (const float*)d_in[10];
    const float* al_ww1 = (const float*)d_in[11];
    const float* ar_ww1 = (const float*)d_in[12];
    const float* b_ww1  = (const float*)d_in[13];
    const float* W_wd1  = (const float*)d_in[14];
    const float* al_wd1 = (const float*)d_in[15];
    const float* ar_wd1 = (const float*)d_in[16];
    const float* b_wd1  = (const float*)d_in[17];
    const int* ww_src   = (const int*)d_in[18];
    const int* ww_dst   = (const int*)d_in[19];
    const int* wd_src   = (const int*)d_in[20];
    const int* wd_dst   = (const int*)d_in[21];

    // ---- workspace carve ----
    char* p = (char*)d_ws;
    __hip_bfloat16* z    = (__hip_bfloat16*)aln(p, (size_t)NW * 1024 * 2);  // 164 MB
    __hip_bfloat16* xwb  = (__hip_bfloat16*)aln(p, (size_t)NW * 256 * 2);
    __hip_bfloat16* xw1b = (__hip_bfloat16*)aln(p, (size_t)NW * 128 * 2);
    __hip_bfloat16* xd1b = (__hip_bfloat16*)aln(p, (size_t)ND * 128 * 2);
    __hip_bfloat16* Wt0  = (__hip_bfloat16*)aln(p, (size_t)1024 * 256 * 2);
    __hip_bfloat16* Wt1  = (__hip_bfloat16*)aln(p, (size_t)1024 * 128 * 2);
    float* el0  = (float*)aln(p, (size_t)NW * 4 * 4);
    float* er0  = (float*)aln(p, (size_t)NW * 4 * 4);
    float* el1  = (float*)aln(p, (size_t)NW * 4 * 4);
    float* Wr0  = (float*)aln(p, 4096);
    float* Wr1  = (float*)aln(p, 4096);
    // deg arrays contiguous (one zero-fill region in util_all)
    int* deg_ww = (int*)aln(p, (size_t)NW * 2 * 4);
    int* deg_wd = (int*)aln(p, (size_t)ND * 2 * 4);
    int* rp_ww  = (int*)aln(p, (size_t)(NW + 1) * 4);
    int* ss_ww  = (int*)aln(p, (size_t)EWW * 4);
    int* rp_wd  = (int*)aln(p, (size_t)(ND + 1) * 4);
    int* ss_wd  = (int*)aln(p, (size_t)EWD * 4);
    int* bsum   = (int*)aln(p, 2048);
    int* bsum_w = bsum;
    int* bsum_d = bsum + 256;

    float* out_xw = (float*)d_out;
    float* out_xd = out_xw + (size_t)NW * 128;

    const int NBW_S = (NW + 1023) / 1024;   // 79
    const int NBD_S = (ND + 1023) / 1024;   // 16

    // ---- fused: cast + weight prep + deg zeroing (one dispatch) ----
    util_all<<<21730, 256, 0, stream>>>((const float4*)xw, (uint2*)xwb,
                                        W_ww0, W_wd0, W_ww1, W_wd1, ar_wd0, ar_wd1,
                                        Wt0, Wt1, Wr0, Wr1, (int4*)deg_ww);

    // ---- fused CSR build ----
    hist2<<<(EWW + 255) / 256, 256, 0, stream>>>(ww_dst, wd_dst, deg_ww, deg_wd);
    scan_block2<<<NBW_S + NBD_S, 256, 0, stream>>>(deg_ww, rp_ww, bsum_w,
                                                   deg_wd, rp_wd, bsum_d, NBW_S);
    add_off2p<<<NBW_S + NBD_S, 256, 0, stream>>>(rp_ww, bsum_w, NBW_S, rp_wd, bsum_d, NBD_S);
    scatter2<<<(EWW + 255) / 256, 256, 0, stream>>>(ww_src, ww_dst, rp_ww, deg_ww + NW, ss_ww,
                                                    wd_src, wd_dst, rp_wd, deg_wd + ND, ss_wd);

    const int GEMM_BLOCKS = 8 * (NW / 128);   // 5000
    const int NBW = (NW + 3) / 4, NBD = (ND + 3) / 4;

    // ================= layer 0 (K=256) =================
    gemm_epi<<<GEMM_BLOCKS, 512, 0, stream>>>(xwb, Wt0, z, al_ww0, ar_ww0, al_wd0,
                                              el0, er0, el1, NW, 256);
    softmax_agg2<<<NBW + NBD, 256, 0, stream>>>(
        rp_ww, ss_ww, el0, er0, b_ww0,
        rp_wd, ss_wd, el1, b_wd0,
        xd, nullptr, Wr0,
        z, nullptr, xw1b, nullptr, xd1b, NBW);

    // ================= layer 1 (K=128) =================
    gemm_epi<<<GEMM_BLOCKS, 512, 0, stream>>>(xw1b, Wt1, z, al_ww1, ar_ww1, al_wd1,
                                              el0, er0, el1, NW, 128);
    softmax_agg2<<<NBW + NBD, 256, 0, stream>>>(
        rp_ww, ss_ww, el0, er0, b_ww1,
        rp_wd, ss_wd, el1, b_wd1,
        nullptr, xd1b, Wr1,
        z, out_xw, nullptr, out_xd, nullptr, NBW);
}